// Round 14
// baseline (620.342 us; speedup 1.0000x reference)
//
#include <hip/hip_runtime.h>
#include <math.h>

#define NROWS 65536
#define NDIM  1024
#define NCLS  20
#define NOUT  40     // both heads concatenated: [0,20) cls, [20,40) det
#define KT    128    // K-tile staged in LDS per iteration
#define RPB   64     // rows per block
#define PAD   129    // LDS row stride (floats): (lane*129+d)%32=(lane+d)%32 -> 2-way free

// ---------------------------------------------------------------------------
// Kernel 0: repack W_cls/W_det ([20][1024] each) into d-major Wt[1024][40]
//           (40 contiguous floats per d -> s_load friendly),
//           and zero the 20-float column-sum accumulator.
// ---------------------------------------------------------------------------
__global__ __launch_bounds__(256) void repack_w_k(
    const float* __restrict__ Wc, const float* __restrict__ Wd,
    float* __restrict__ Wt, float* __restrict__ colsum)
{
    int i = blockIdx.x * 256 + threadIdx.x;   // exactly 40960 threads
    int d = i / NOUT;
    int c = i % NOUT;
    float v = (c < NCLS) ? Wc[c * NDIM + d] : Wd[(c - NCLS) * NDIM + d];
    Wt[i] = v;
    if (i < NCLS) colsum[i] = 0.0f;
}

// ---------------------------------------------------------------------------
// Kernel 1: fused dual-head GEMM + softmax pieces, LDS-staged for coalescing.
//   Block = 256 threads = 4 waves, 64 rows, K tiled by 128.
//   Load phase: coalesced float4 (32 lanes = 512 contiguous bytes) -> LDS
//   tile [64][129]. Compute: wave w owns d in [32w,32w+32); lane = row;
//   xs from LDS (conflict-free), W from SGPRs (wave-uniform d); acc[40].
//   Tree-reduce partial sums across 4 waves (reusing the tile LDS), then
//   wave 0 runs the fused epilogue: det exp + colsum atomics; cls softmax;
//   writes pred_cls * exp_det.
// ---------------------------------------------------------------------------
__global__ __launch_bounds__(256) void main_gemm_k(
    const float* __restrict__ x,   const float* __restrict__ Wt,
    const float* __restrict__ bc,  const float* __restrict__ bd,
    float* __restrict__ out,       float* __restrict__ colsum)
{
    const int tid  = threadIdx.x;
    const int lane = tid & 63;
    const int w    = tid >> 6;                            // 0..3
    const int wu   = __builtin_amdgcn_readfirstlane(w);   // wave-uniform
    const int row0 = blockIdx.x * RPB;

    // x-tile (64*129 floats = 33 KB) ∪ reduction area (40*128 = 20 KB)
    __shared__ float smem[RPB * PAD];

    // staging coords: 8 passes x (8 rows x 128 floats); coalesced float4
    const int sr = tid >> 5;          // 0..7 row-within-pass
    const int sc = (tid & 31) * 4;    // 0..124 float offset

    float acc[NOUT];
#pragma unroll
    for (int c = 0; c < NOUT; ++c) acc[c] = 0.0f;

    for (int t = 0; t < NDIM / KT; ++t) {
        // ---- load phase: issue all 8 global loads, then write LDS ----
        float4 v[8];
#pragma unroll
        for (int p = 0; p < 8; ++p) {
            const int r = p * 8 + sr;
            v[p] = *(const float4*)(x + (size_t)(row0 + r) * NDIM + t * KT + sc);
        }
#pragma unroll
        for (int p = 0; p < 8; ++p) {
            const int r = p * 8 + sr;
            smem[r * PAD + sc + 0] = v[p].x;
            smem[r * PAD + sc + 1] = v[p].y;
            smem[r * PAD + sc + 2] = v[p].z;
            smem[r * PAD + sc + 3] = v[p].w;
        }
        __syncthreads();

        // ---- compute phase: wave w covers d_local in [32w, 32w+32) ----
        const float* __restrict__ wt = Wt + (size_t)(t * KT + wu * 32) * NOUT;
#pragma unroll 4
        for (int i = 0; i < 32; ++i) {
            const float xs = smem[lane * PAD + wu * 32 + i];
#pragma unroll
            for (int c = 0; c < NOUT; ++c)
                acc[c] = fmaf(xs, wt[i * NOUT + c], acc[c]);
        }
        __syncthreads();
    }

    // ---- tree reduction across the 4 waves (reuse smem; [40][128]) ----
    if (w >= 2) {
        const int s = tid - 128;
#pragma unroll
        for (int c = 0; c < NOUT; ++c) smem[c * 128 + s] = acc[c];
    }
    __syncthreads();
    if (w < 2) {
#pragma unroll
        for (int c = 0; c < NOUT; ++c) acc[c] += smem[c * 128 + tid];
    }
    __syncthreads();
    if (w == 1) {
#pragma unroll
        for (int c = 0; c < NOUT; ++c) smem[c * 128 + (tid - 64)] = acc[c];
    }
    __syncthreads();

    if (w == 0) {
#pragma unroll
        for (int c = 0; c < NOUT; ++c) acc[c] += smem[c * 128 + lane];

        // ---- det head: exp in-place (logits are O(+-7), safe without max)
#pragma unroll
        for (int c = 0; c < NCLS; ++c) acc[NCLS + c] = expf(acc[NCLS + c] + bd[c]);

        // per-class wave reduction -> one atomicAdd per class from lane 0
#pragma unroll
        for (int c = 0; c < NCLS; ++c) {
            float v2 = acc[NCLS + c];
            v2 += __shfl_xor(v2, 32, 64);
            v2 += __shfl_xor(v2, 16, 64);
            v2 += __shfl_xor(v2,  8, 64);
            v2 += __shfl_xor(v2,  4, 64);
            v2 += __shfl_xor(v2,  2, 64);
            v2 += __shfl_xor(v2,  1, 64);
            if (lane == 0) atomicAdd(&colsum[c], v2);
        }

        // ---- cls head: row softmax over 20 classes, in-place
        float m = -3.402823466e+38f;
#pragma unroll
        for (int c = 0; c < NCLS; ++c) { acc[c] += bc[c]; m = fmaxf(m, acc[c]); }
        float s = 0.0f;
#pragma unroll
        for (int c = 0; c < NCLS; ++c) { acc[c] = expf(acc[c] - m); s += acc[c]; }
        const float inv = 1.0f / s;

        float* __restrict__ orow = out + (size_t)(row0 + lane) * NCLS;
#pragma unroll
        for (int i = 0; i < 5; ++i) {
            float4 o;
            o.x = acc[4*i + 0] * inv * acc[NCLS + 4*i + 0];
            o.y = acc[4*i + 1] * inv * acc[NCLS + 4*i + 1];
            o.z = acc[4*i + 2] * inv * acc[NCLS + 4*i + 2];
            o.w = acc[4*i + 3] * inv * acc[NCLS + 4*i + 3];
            ((float4*)orow)[i] = o;
        }
    }
}

// ---------------------------------------------------------------------------
// Kernel 2: invert the 20 column sums.
// ---------------------------------------------------------------------------
__global__ void finalize_k(const float* __restrict__ colsum, float* __restrict__ inv)
{
    int c = threadIdx.x;
    if (c < NCLS) inv[c] = 1.0f / colsum[c];
}

// ---------------------------------------------------------------------------
// Kernel 3: scale out[r][c] (= pred_cls * exp_det) by 1/colsum[c].
//   float4 per thread; base = (4i)%20 is a multiple of 4 <= 16, never wraps.
// ---------------------------------------------------------------------------
__global__ __launch_bounds__(256) void scale_k(
    float* __restrict__ out, const float* __restrict__ inv)
{
    int i = blockIdx.x * 256 + threadIdx.x;      // exactly 327680 threads
    int base = (i * 4) % NCLS;
    float4 v = ((float4*)out)[i];
    v.x *= inv[base + 0];
    v.y *= inv[base + 1];
    v.z *= inv[base + 2];
    v.w *= inv[base + 3];
    ((float4*)out)[i] = v;
}

// ---------------------------------------------------------------------------
extern "C" void kernel_launch(void* const* d_in, const int* in_sizes, int n_in,
                              void* d_out, int out_size, void* d_ws, size_t ws_size,
                              hipStream_t stream)
{
    const float* x  = (const float*)d_in[0];
    const float* Wc = (const float*)d_in[1];
    const float* bc = (const float*)d_in[2];
    const float* Wd = (const float*)d_in[3];
    const float* bd = (const float*)d_in[4];
    float* out = (float*)d_out;

    // workspace layout (fp32): Wt[1024*40] | colsum[20] | inv[20]
    float* Wt     = (float*)d_ws;
    float* colsum = Wt + NDIM * NOUT;
    float* inv    = colsum + NCLS;

    repack_w_k<<<(NDIM * NOUT) / 256, 256, 0, stream>>>(Wc, Wd, Wt, colsum);
    main_gemm_k<<<NROWS / RPB, 256, 0, stream>>>(x, Wt, bc, bd, out, colsum);
    finalize_k<<<1, 64, 0, stream>>>(colsum, inv);
    scale_k<<<(NROWS * NCLS / 4) / 256, 256, 0, stream>>>(out, inv);
}